// Round 2
// baseline (1839.080 us; speedup 1.0000x reference)
//
#include <hip/hip_runtime.h>
#include <math.h>

#define HH 128
#define WW 128
#define BB 4
#define HW (HH*WW)

// ---------------------------------------------------------------------------
// 3x3 conv, stride 1, pad 1, NCHW, f32. Direct conv with LDS input tile.
// Block = 256 threads; output tile 16(h) x 32(w), 2 pixels per thread.
// 8 input channels staged per LDS round (one barrier pair per 8 channels).
// CONCAT=true: input = cat([inA(64), inB(64), inC(2)]).
// ---------------------------------------------------------------------------
template<int CIN, int OCPB, bool RELU, bool CONCAT>
__global__ __launch_bounds__(256) void conv3x3_k(
    const float* __restrict__ inA, const float* __restrict__ inB,
    const float* __restrict__ inC,
    const float* __restrict__ wgt, const float* __restrict__ bias,
    float* __restrict__ out, int OCtot)
{
    __shared__ float tile[8][18 * 34];

    const int tileId = blockIdx.x;          // 32 tiles: 8 rows x 4 cols
    const int h0 = (tileId >> 2) << 4;
    const int w0 = (tileId & 3) << 5;
    const int oc0 = blockIdx.y * OCPB;
    const int b = blockIdx.z;
    const int t = threadIdx.x;
    const int px = t & 15, py = t >> 4;
    const int oh = h0 + py;

    float acc0[OCPB], acc1[OCPB];
#pragma unroll
    for (int o = 0; o < OCPB; ++o) { acc0[o] = bias[oc0 + o]; acc1[o] = acc0[o]; }

    for (int c0 = 0; c0 < CIN; c0 += 8) {
        const int nc = (CIN - c0 < 8) ? (CIN - c0) : 8;
        __syncthreads();
        for (int cc = 0; cc < nc; ++cc) {
            const int c = c0 + cc;
            const float* plane;
            if (CONCAT) {
                if (c < 64)       plane = inA + ((size_t)b * 64 + c) * HW;
                else if (c < 128) plane = inB + ((size_t)b * 64 + (c - 64)) * HW;
                else              plane = inC + ((size_t)b * 2 + (c - 128)) * HW;
            } else {
                plane = inA + ((size_t)b * CIN + c) * HW;
            }
            for (int i = t; i < 18 * 34; i += 256) {
                const int ty = i / 34, tx = i % 34;
                const int gy = h0 - 1 + ty, gx = w0 - 1 + tx;
                float v = 0.f;
                if (gy >= 0 && gy < HH && gx >= 0 && gx < WW) v = plane[gy * WW + gx];
                tile[cc][i] = v;
            }
        }
        __syncthreads();

        for (int cc = 0; cc < nc; ++cc) {
            float v[18];
#pragma unroll
            for (int ky = 0; ky < 3; ++ky)
#pragma unroll
                for (int kx = 0; kx < 3; ++kx) {
                    v[ky * 3 + kx]     = tile[cc][(py + ky) * 34 + px + kx];
                    v[9 + ky * 3 + kx] = tile[cc][(py + ky) * 34 + px + 16 + kx];
                }
            const float* wp = wgt + ((size_t)oc0 * CIN + c0 + cc) * 9;
#pragma unroll
            for (int o = 0; o < OCPB; ++o) {
                const float* w9 = wp + (size_t)o * CIN * 9;
#pragma unroll
                for (int k = 0; k < 9; ++k) {
                    acc0[o] = fmaf(w9[k], v[k],     acc0[o]);
                    acc1[o] = fmaf(w9[k], v[9 + k], acc1[o]);
                }
            }
        }
    }

#pragma unroll
    for (int o = 0; o < OCPB; ++o) {
        float r0 = acc0[o], r1 = acc1[o];
        if (RELU) { r0 = (r0 >= 0.f) ? r0 : 0.1f * r0; r1 = (r1 >= 0.f) ? r1 : 0.1f * r1; }
        float* orow = out + (((size_t)b * OCtot + oc0 + o) * HH + oh) * WW + w0;
        orow[px]      = r0;
        orow[px + 16] = r1;
    }
}

// ---------------------------------------------------------------------------
// Transpose x [B][64][HW] -> xt [B][HW][64] (channel-last) so each deform tap
// reads its group's 8 channels as two float4s.
// ---------------------------------------------------------------------------
__global__ __launch_bounds__(256) void transpose_x_k(
    const float* __restrict__ x, float* __restrict__ xt)
{
    __shared__ float lds[64][65];
    const int p0 = blockIdx.x * 64;
    const int b  = blockIdx.y;
    const int t  = threadIdx.x;
    for (int i = t; i < 4096; i += 256) {
        const int c = i >> 6, p = i & 63;
        lds[p][c] = x[((size_t)b * 64 + c) * HW + p0 + p];
    }
    __syncthreads();
    for (int i = t; i < 4096; i += 256) {
        const int p = i >> 6, c = i & 63;
        xt[((size_t)b * HW + p0 + p) * 64 + c] = lds[p][c];
    }
}

// ---------------------------------------------------------------------------
// Transpose deform weight [O=64][C=64][9] -> [(g*9+k)*8+c][O=64]
// ---------------------------------------------------------------------------
__global__ void transpose_w_k(const float* __restrict__ wsrc, float* __restrict__ wdst)
{
    int i = blockIdx.x * 256 + threadIdx.x;   // over 64*64*9 = 36864
    if (i >= 64 * 64 * 9) return;
    int o  = i / 576;
    int r  = i % 576;
    int ch = r / 9;
    int k  = r % 9;
    int g = ch >> 3, c = ch & 7;
    wdst[(((g * 9 + k) * 8) + c) * 64 + o] = wsrc[i];
}

// ---------------------------------------------------------------------------
// Deformable conv. grid = (B*HW/256, 4): each block computes 16 output
// channels (oc0 = blockIdx.y*16) for 256 pixels. Channel-last x (xt).
// ---------------------------------------------------------------------------
__global__ __launch_bounds__(256) void deform_k(
    const float* __restrict__ xt, const float* __restrict__ o4,
    const float* __restrict__ flow, const float* __restrict__ wt,
    const float* __restrict__ bias, float* __restrict__ out)
{
    const int tid = blockIdx.x * 256 + threadIdx.x;   // 0 .. B*H*W-1
    const int w = tid & (WW - 1);
    const int h = (tid >> 7) & (HH - 1);
    const int b = tid >> 14;
    const int oc0 = blockIdx.y * 16;

    float acc[16];
#pragma unroll
    for (int o = 0; o < 16; ++o) acc[o] = 0.f;

    const size_t pix = (size_t)h * WW + w;
    const float* o4b = o4 + (size_t)b * 216 * HW + pix;
    const float fy = flow[((size_t)b * 2 + 1) * HW + pix];
    const float fx = flow[((size_t)b * 2 + 0) * HW + pix];
    const float* xb = xt + (size_t)b * HW * 64;

    for (int g = 0; g < 8; ++g) {
#pragma unroll
        for (int k = 0; k < 9; ++k) {
            const int coff = g * 18 + k * 2;
            const float oy = o4b[(size_t)coff * HW];
            const float ox = o4b[(size_t)(coff + 1) * HW];
            float m = o4b[(size_t)(144 + g * 9 + k) * HW];
            m = 1.f / (1.f + expf(-m));

            const float py = 10.f * tanhf(oy) + fy + (float)h + (float)(k / 3 - 1);
            const float px = 10.f * tanhf(ox) + fx + (float)w + (float)(k % 3 - 1);

            const float y0f = floorf(py), x0f = floorf(px);
            const float ly = py - y0f, lx = px - x0f;
            const int iy0 = (int)y0f, ix0 = (int)x0f;
            const int iy1 = iy0 + 1,  ix1 = ix0 + 1;

            const float vy0 = (iy0 >= 0 && iy0 < HH) ? 1.f : 0.f;
            const float vy1 = (iy1 >= 0 && iy1 < HH) ? 1.f : 0.f;
            const float vx0 = (ix0 >= 0 && ix0 < WW) ? 1.f : 0.f;
            const float vx1 = (ix1 >= 0 && ix1 < WW) ? 1.f : 0.f;

            const int cy0 = min(max(iy0, 0), HH - 1);
            const int cy1 = min(max(iy1, 0), HH - 1);
            const int cx0 = min(max(ix0, 0), WW - 1);
            const int cx1 = min(max(ix1, 0), WW - 1);

            const float w00 = (1.f - ly) * (1.f - lx) * vy0 * vx0 * m;
            const float w01 = (1.f - ly) * lx         * vy0 * vx1 * m;
            const float w10 = ly         * (1.f - lx) * vy1 * vx0 * m;
            const float w11 = ly         * lx         * vy1 * vx1 * m;

            const int i00 = cy0 * WW + cx0, i01 = cy0 * WW + cx1;
            const int i10 = cy1 * WW + cx0, i11 = cy1 * WW + cx1;

            const float4* q00 = (const float4*)(xb + ((size_t)i00 << 6) + (g << 3));
            const float4* q01 = (const float4*)(xb + ((size_t)i01 << 6) + (g << 3));
            const float4* q10 = (const float4*)(xb + ((size_t)i10 << 6) + (g << 3));
            const float4* q11 = (const float4*)(xb + ((size_t)i11 << 6) + (g << 3));
            const float4 a0 = q00[0], a1 = q00[1];
            const float4 b0 = q01[0], b1 = q01[1];
            const float4 c0 = q10[0], c1 = q10[1];
            const float4 d0 = q11[0], d1 = q11[1];

            float s[8];
            s[0] = w00 * a0.x + w01 * b0.x + w10 * c0.x + w11 * d0.x;
            s[1] = w00 * a0.y + w01 * b0.y + w10 * c0.y + w11 * d0.y;
            s[2] = w00 * a0.z + w01 * b0.z + w10 * c0.z + w11 * d0.z;
            s[3] = w00 * a0.w + w01 * b0.w + w10 * c0.w + w11 * d0.w;
            s[4] = w00 * a1.x + w01 * b1.x + w10 * c1.x + w11 * d1.x;
            s[5] = w00 * a1.y + w01 * b1.y + w10 * c1.y + w11 * d1.y;
            s[6] = w00 * a1.z + w01 * b1.z + w10 * c1.z + w11 * d1.z;
            s[7] = w00 * a1.w + w01 * b1.w + w10 * c1.w + w11 * d1.w;

            const float* wrow = wt + (size_t)(g * 9 + k) * 512 + oc0;
#pragma unroll
            for (int c = 0; c < 8; ++c) {
#pragma unroll
                for (int o = 0; o < 16; ++o)
                    acc[o] = fmaf(wrow[c * 64 + o], s[c], acc[o]);
            }
        }
    }

#pragma unroll
    for (int o = 0; o < 16; ++o)
        out[((size_t)b * 64 + oc0 + o) * HW + pix] = acc[o] + bias[oc0 + o];
}

// ---------------------------------------------------------------------------
extern "C" void kernel_launch(void* const* d_in, const int* in_sizes, int n_in,
                              void* d_out, int out_size, void* d_ws, size_t ws_size,
                              hipStream_t stream)
{
    const float* x     = (const float*)d_in[0];
    const float* xw    = (const float*)d_in[1];
    const float* xc    = (const float*)d_in[2];
    const float* flow  = (const float*)d_in[3];
    const float* w1    = (const float*)d_in[4];
    const float* b1    = (const float*)d_in[5];
    const float* w2    = (const float*)d_in[6];
    const float* b2    = (const float*)d_in[7];
    const float* w3    = (const float*)d_in[8];
    const float* b3    = (const float*)d_in[9];
    const float* w4    = (const float*)d_in[10];
    const float* b4    = (const float*)d_in[11];
    const float* wt    = (const float*)d_in[12];
    const float* bias  = (const float*)d_in[13];
    float* out = (float*)d_out;

    char* ws = (char*)d_ws;
    // ws layout (total ~90.3 MB, same footprint as the round-1 passing run):
    //   slot0 [0,16.8M)      : o1, later o3
    //   slot1 [16.8M,33.6M)  : o2, later xt (channel-last x)
    //   slot2 [33.6M,90.2M)  : o4
    //   slot3 [90.2M,90.35M) : transposed deform weight
    float* o1  = (float*)(ws);
    float* o2  = (float*)(ws + 16777216);
    float* o4  = (float*)(ws + 2 * 16777216);
    float* wtr = (float*)(ws + 2 * 16777216 + 56623104);
    float* xt  = o2;   // reuses slot1 after conv3 has consumed o2

    const dim3 blk(256);

    // conv1: 130 -> 64, lrelu (concat input)
    conv3x3_k<130, 16, true, true><<<dim3(32, 4, BB), blk, 0, stream>>>(
        xw, xc, flow, w1, b1, o1, 64);
    // conv2: 64 -> 64, lrelu
    conv3x3_k<64, 16, true, false><<<dim3(32, 4, BB), blk, 0, stream>>>(
        o1, nullptr, nullptr, w2, b2, o2, 64);
    // conv3: 64 -> 64, lrelu   (write into slot0)
    conv3x3_k<64, 16, true, false><<<dim3(32, 4, BB), blk, 0, stream>>>(
        o2, nullptr, nullptr, w3, b3, o1, 64);
    // x -> channel-last (slot1 is dead after conv3)
    transpose_x_k<<<dim3(HW / 64, BB), blk, 0, stream>>>(x, xt);
    // conv4: 64 -> 216, no act
    conv3x3_k<64, 24, false, false><<<dim3(32, 9, BB), blk, 0, stream>>>(
        o1, nullptr, nullptr, w4, b4, o4, 216);

    transpose_w_k<<<dim3((36864 + 255) / 256), blk, 0, stream>>>(wt, wtr);

    deform_k<<<dim3((BB * HW) / 256, 4), blk, 0, stream>>>(
        xt, o4, flow, wtr, bias, out);
}

// Round 3
// 1100.316 us; speedup vs baseline: 1.6714x; 1.6714x over previous
//
#include <hip/hip_runtime.h>
#include <math.h>

#define HH 128
#define WW 128
#define BB 4
#define HW (HH*WW)

// ---------------------------------------------------------------------------
// 3x3 conv, stride 1, pad 1, NCHW, f32 — exact round-1 template (known good).
// Block = 256 threads = 16x16 output pixels, OCPB output channels per block.
// ---------------------------------------------------------------------------
template<int CIN, int OCPB, bool RELU, bool CONCAT>
__global__ __launch_bounds__(256) void conv3x3_k(
    const float* __restrict__ inA, const float* __restrict__ inB,
    const float* __restrict__ inC,
    const float* __restrict__ wgt, const float* __restrict__ bias,
    float* __restrict__ out, int OCtot)
{
    __shared__ float tile[18 * 18];

    const int tileId = blockIdx.x;          // 64 tiles (8x8)
    const int h0 = (tileId >> 3) << 4;
    const int w0 = (tileId & 7) << 4;
    const int oc0 = blockIdx.y * OCPB;
    const int b = blockIdx.z;
    const int t = threadIdx.x;
    const int px = t & 15, py = t >> 4;
    const int oh = h0 + py, ow = w0 + px;

    float acc[OCPB];
#pragma unroll
    for (int o = 0; o < OCPB; ++o) acc[o] = bias[oc0 + o];

    for (int c = 0; c < CIN; ++c) {
        const float* plane;
        if (CONCAT) {
            if (c < 64)       plane = inA + ((size_t)b * 64 + c) * HW;
            else if (c < 128) plane = inB + ((size_t)b * 64 + (c - 64)) * HW;
            else              plane = inC + ((size_t)b * 2 + (c - 128)) * HW;
        } else {
            plane = inA + ((size_t)b * CIN + c) * HW;
        }

        __syncthreads();
        for (int i = t; i < 18 * 18; i += 256) {
            const int ty = i / 18, tx = i % 18;
            const int gy = h0 - 1 + ty, gx = w0 - 1 + tx;
            float v = 0.f;
            if (gy >= 0 && gy < HH && gx >= 0 && gx < WW) v = plane[gy * WW + gx];
            tile[i] = v;
        }
        __syncthreads();

        float v[9];
#pragma unroll
        for (int ky = 0; ky < 3; ++ky)
#pragma unroll
            for (int kx = 0; kx < 3; ++kx)
                v[ky * 3 + kx] = tile[(py + ky) * 18 + (px + kx)];

        const float* wp = wgt + ((size_t)oc0 * CIN + c) * 9;
#pragma unroll
        for (int o = 0; o < OCPB; ++o) {
            const float* w9 = wp + (size_t)o * CIN * 9;
#pragma unroll
            for (int k = 0; k < 9; ++k)
                acc[o] = fmaf(w9[k], v[k], acc[o]);
        }
    }

#pragma unroll
    for (int o = 0; o < OCPB; ++o) {
        float r = acc[o];
        if (RELU) r = (r >= 0.f) ? r : 0.1f * r;
        out[(((size_t)b * OCtot + oc0 + o) * HH + oh) * WW + ow] = r;
    }
}

// ---------------------------------------------------------------------------
// x [b][64][HW] -> xq [b][16][HW] of float4 (channel quads): corner read of a
// deform group's 8 channels = 2 float4 loads, 16B granularity (no 256B-record
// overfetch like full channel-last).
// ---------------------------------------------------------------------------
__global__ __launch_bounds__(256) void transpose_xq_k(
    const float* __restrict__ x, float4* __restrict__ xq)
{
    const int i = blockIdx.x * 256 + threadIdx.x;   // B*16*HW
    const int pix = i & (HW - 1);
    const int q = (i >> 14) & 15;
    const int b = i >> 18;
    const float* xp = x + ((size_t)(b * 64 + q * 4)) * HW + pix;
    float4 v;
    v.x = xp[0]; v.y = xp[HW]; v.z = xp[2 * HW]; v.w = xp[3 * HW];
    xq[(size_t)(b * 16 + q) * HW + pix] = v;
}

// ---------------------------------------------------------------------------
// Deform weight [O=64][C=64][9] -> wtr[j=(g*9+k)*8+c][O=64]
// ---------------------------------------------------------------------------
__global__ void transpose_w_k(const float* __restrict__ wsrc, float* __restrict__ wdst)
{
    int i = blockIdx.x * 256 + threadIdx.x;   // 64*64*9 = 36864
    if (i >= 64 * 64 * 9) return;
    int o  = i / 576;
    int r  = i % 576;
    int ch = r / 9;
    int k  = r % 9;
    int g = ch >> 3, c = ch & 7;
    wdst[(((g * 9 + k) * 8) + c) * 64 + o] = wsrc[i];
}

__device__ __forceinline__ unsigned pk_bf16(float lo, float hi) {
    unsigned a = __float_as_uint(lo), b = __float_as_uint(hi);
    return ((a + 0x8000u) >> 16) | ((b + 0x8000u) & 0xffff0000u);
}

// ---------------------------------------------------------------------------
// Fused deform: block = 32 pixels. Phase 1: thread=(px,g) computes bilinear
// samples for 9 taps x 8 channels -> bf16 in LDS. Phase 2: thread=(px,oc8)
// contracts s[576] x wtr[576][64] from LDS. One barrier, no HBM round-trip.
// ---------------------------------------------------------------------------
__global__ __launch_bounds__(256) void deform_fused_k(
    const float4* __restrict__ xq, const float* __restrict__ o4,
    const float* __restrict__ flow, const float* __restrict__ wtr,
    const float* __restrict__ bias, float* __restrict__ out)
{
    __shared__ uint4 sv[32][74];   // 37,888 B -> 4 blocks/CU

    const int bid = blockIdx.x;            // B*HW/32 = 2048
    const int b = bid >> 9;
    const int pix0 = (bid & 511) << 5;
    const int t = threadIdx.x;

    // ---------------- gather phase: (g = t>>5, px = t&31) ------------------
    {
        const int gpx = t & 31, g = t >> 5;
        const int pix = pix0 + gpx;
        const int h = pix >> 7, w = pix & (WW - 1);
        const float fy = flow[((size_t)b * 2 + 1) * HW + pix];
        const float fx = flow[((size_t)b * 2 + 0) * HW + pix];
        const float* ob = o4 + (size_t)b * 216 * HW + pix;
        const float4* q0 = xq + (size_t)(b * 16 + g * 2) * HW;
        const float4* q1 = q0 + HW;

#pragma unroll
        for (int k = 0; k < 9; ++k) {
            const float oy = ob[(size_t)(g * 18 + k * 2) * HW];
            const float ox = ob[(size_t)(g * 18 + k * 2 + 1) * HW];
            float mm = ob[(size_t)(144 + g * 9 + k) * HW];
            mm = __builtin_amdgcn_rcpf(1.f + __expf(-mm));

            const float ay = fabsf(oy), ax = fabsf(ox);
            const float ey = __expf(-2.f * ay), ex = __expf(-2.f * ax);
            float ty = (1.f - ey) * __builtin_amdgcn_rcpf(1.f + ey);
            float tx = (1.f - ex) * __builtin_amdgcn_rcpf(1.f + ex);
            ty = copysignf(ty, oy); tx = copysignf(tx, ox);

            const float ppy = 10.f * ty + fy + (float)(h + k / 3 - 1);
            const float ppx = 10.f * tx + fx + (float)(w + k % 3 - 1);

            const float y0f = floorf(ppy), x0f = floorf(ppx);
            const float ly = ppy - y0f, lx = ppx - x0f;
            const int iy0 = (int)y0f, ix0 = (int)x0f;
            const int iy1 = iy0 + 1,  ix1 = ix0 + 1;

            const float vy0 = (iy0 >= 0 && iy0 < HH) ? 1.f : 0.f;
            const float vy1 = (iy1 >= 0 && iy1 < HH) ? 1.f : 0.f;
            const float vx0 = (ix0 >= 0 && ix0 < WW) ? 1.f : 0.f;
            const float vx1 = (ix1 >= 0 && ix1 < WW) ? 1.f : 0.f;

            const int cy0 = min(max(iy0, 0), HH - 1);
            const int cy1 = min(max(iy1, 0), HH - 1);
            const int cx0 = min(max(ix0, 0), WW - 1);
            const int cx1 = min(max(ix1, 0), WW - 1);

            const float w00 = (1.f - ly) * (1.f - lx) * vy0 * vx0 * mm;
            const float w01 = (1.f - ly) * lx         * vy0 * vx1 * mm;
            const float w10 = ly         * (1.f - lx) * vy1 * vx0 * mm;
            const float w11 = ly         * lx         * vy1 * vx1 * mm;

            const int i00 = cy0 * WW + cx0, i01 = cy0 * WW + cx1;
            const int i10 = cy1 * WW + cx0, i11 = cy1 * WW + cx1;

            const float4 a0 = q0[i00], a1 = q1[i00];
            const float4 b0 = q0[i01], b1 = q1[i01];
            const float4 c0 = q0[i10], c1 = q1[i10];
            const float4 d0 = q0[i11], d1 = q1[i11];

            float s0 = w00 * a0.x + w01 * b0.x + w10 * c0.x + w11 * d0.x;
            float s1 = w00 * a0.y + w01 * b0.y + w10 * c0.y + w11 * d0.y;
            float s2 = w00 * a0.z + w01 * b0.z + w10 * c0.z + w11 * d0.z;
            float s3 = w00 * a0.w + w01 * b0.w + w10 * c0.w + w11 * d0.w;
            float s4 = w00 * a1.x + w01 * b1.x + w10 * c1.x + w11 * d1.x;
            float s5 = w00 * a1.y + w01 * b1.y + w10 * c1.y + w11 * d1.y;
            float s6 = w00 * a1.z + w01 * b1.z + w10 * c1.z + w11 * d1.z;
            float s7 = w00 * a1.w + w01 * b1.w + w10 * c1.w + w11 * d1.w;

            uint4 P;
            P.x = pk_bf16(s0, s1);
            P.y = pk_bf16(s2, s3);
            P.z = pk_bf16(s4, s5);
            P.w = pk_bf16(s6, s7);
            sv[gpx][g * 9 + k] = P;
        }
    }
    __syncthreads();

    // ---------------- contraction phase: (px = t>>3, oc0 = (t&7)*8) --------
    {
        const int px = t >> 3, oc0 = (t & 7) << 3;
        const int pix = pix0 + px;
        float acc[8];
#pragma unroll
        for (int o = 0; o < 8; ++o) acc[o] = 0.f;

        for (int g = 0; g < 8; ++g) {
#pragma unroll
            for (int k = 0; k < 9; ++k) {
                const uint4 qv = sv[px][g * 9 + k];
                float sc[8];
                sc[0] = __uint_as_float(qv.x << 16);
                sc[1] = __uint_as_float(qv.x & 0xffff0000u);
                sc[2] = __uint_as_float(qv.y << 16);
                sc[3] = __uint_as_float(qv.y & 0xffff0000u);
                sc[4] = __uint_as_float(qv.z << 16);
                sc[5] = __uint_as_float(qv.z & 0xffff0000u);
                sc[6] = __uint_as_float(qv.w << 16);
                sc[7] = __uint_as_float(qv.w & 0xffff0000u);

                const float* wp = wtr + (size_t)((g * 9 + k) * 8) * 64 + oc0;
#pragma unroll
                for (int c = 0; c < 8; ++c) {
                    const float4 wa = *(const float4*)(wp + c * 64);
                    const float4 wb = *(const float4*)(wp + c * 64 + 4);
                    acc[0] = fmaf(sc[c], wa.x, acc[0]);
                    acc[1] = fmaf(sc[c], wa.y, acc[1]);
                    acc[2] = fmaf(sc[c], wa.z, acc[2]);
                    acc[3] = fmaf(sc[c], wa.w, acc[3]);
                    acc[4] = fmaf(sc[c], wb.x, acc[4]);
                    acc[5] = fmaf(sc[c], wb.y, acc[5]);
                    acc[6] = fmaf(sc[c], wb.z, acc[6]);
                    acc[7] = fmaf(sc[c], wb.w, acc[7]);
                }
            }
        }

#pragma unroll
        for (int o = 0; o < 8; ++o)
            out[((size_t)b * 64 + oc0 + o) * HW + pix] = acc[o] + bias[oc0 + o];
    }
}

// ---------------------------------------------------------------------------
extern "C" void kernel_launch(void* const* d_in, const int* in_sizes, int n_in,
                              void* d_out, int out_size, void* d_ws, size_t ws_size,
                              hipStream_t stream)
{
    const float* x     = (const float*)d_in[0];
    const float* xw    = (const float*)d_in[1];
    const float* xc    = (const float*)d_in[2];
    const float* flow  = (const float*)d_in[3];
    const float* w1    = (const float*)d_in[4];
    const float* b1    = (const float*)d_in[5];
    const float* w2    = (const float*)d_in[6];
    const float* b2    = (const float*)d_in[7];
    const float* w3    = (const float*)d_in[8];
    const float* b3    = (const float*)d_in[9];
    const float* w4    = (const float*)d_in[10];
    const float* b4    = (const float*)d_in[11];
    const float* wt    = (const float*)d_in[12];
    const float* bias  = (const float*)d_in[13];
    float* out = (float*)d_out;

    char* ws = (char*)d_ws;
    // ws layout (identical 90.3 MB footprint to rounds 1-2):
    //   slot0 [0,16.8M)      : o1, later o3
    //   slot1 [16.8M,33.6M)  : o2, later xq (channel-quad x)
    //   slot2 [33.6M,90.2M)  : o4
    //   slot3 [90.2M,90.35M) : transposed deform weight
    float* o1  = (float*)(ws);
    float* o2  = (float*)(ws + 16777216);
    float* o4  = (float*)(ws + 2 * 16777216);
    float* wtr = (float*)(ws + 2 * 16777216 + 56623104);
    float4* xq = (float4*)o2;   // slot1 reused after conv3 consumes o2

    const dim3 blk(256);

    // conv1: 130 -> 64, lrelu (concat input)
    conv3x3_k<130, 16, true, true><<<dim3(64, 4, BB), blk, 0, stream>>>(
        xw, xc, flow, w1, b1, o1, 64);
    // conv2: 64 -> 64, lrelu
    conv3x3_k<64, 16, true, false><<<dim3(64, 4, BB), blk, 0, stream>>>(
        o1, nullptr, nullptr, w2, b2, o2, 64);
    // conv3: 64 -> 64, lrelu   (into slot0)
    conv3x3_k<64, 16, true, false><<<dim3(64, 4, BB), blk, 0, stream>>>(
        o2, nullptr, nullptr, w3, b3, o1, 64);
    // x -> channel-quad layout (slot1 dead after conv3)
    transpose_xq_k<<<dim3(BB * 16 * HW / 256), blk, 0, stream>>>(x, xq);
    // conv4: 64 -> 216, no act
    conv3x3_k<64, 24, false, false><<<dim3(64, 9, BB), blk, 0, stream>>>(
        o1, nullptr, nullptr, w4, b4, o4, 216);

    transpose_w_k<<<dim3((36864 + 255) / 256), blk, 0, stream>>>(wt, wtr);

    deform_fused_k<<<dim3(BB * HW / 32), blk, 0, stream>>>(
        xq, o4, flow, wtr, bias, out);
}

// Round 4
// 705.933 us; speedup vs baseline: 2.6052x; 1.5587x over previous
//
#include <hip/hip_runtime.h>
#include <math.h>

#define HH 128
#define WW 128
#define BB 4
#define HW (HH*WW)

typedef unsigned short u16;
typedef unsigned int u32;
typedef __bf16 bf16x8 __attribute__((ext_vector_type(8)));
typedef float f32x4 __attribute__((ext_vector_type(4)));

__device__ __forceinline__ u16 f2bf(float x) {
    u32 u = __float_as_uint(x);
    return (u16)((u + 0x7fffu + ((u >> 16) & 1u)) >> 16);
}
__device__ __forceinline__ float bf2f(u16 h) {
    return __uint_as_float(((u32)h) << 16);
}
__device__ __forceinline__ bf16x8 ld8(const u16* p) {
    union { uint4 u; bf16x8 v; } c;
    c.u = *(const uint4*)p;
    return c.v;
}

// ---------------------------------------------------------------------------
// Weight split-prep: src [OC][CIN][3][3] f32 -> dh/dl [OCpad][9][CINpad] bf16
// (hi = rne(w), lo = rne(w - hi); zero-padded in oc and cin)
// ---------------------------------------------------------------------------
__global__ void split_w_k(const float* __restrict__ src, u16* __restrict__ dh,
                          u16* __restrict__ dl, int OC, int OCpad, int CIN, int CINpad)
{
    const int i = blockIdx.x * 256 + threadIdx.x;
    const int tot = OCpad * 9 * CINpad;
    if (i >= tot) return;
    const int oc = i / (9 * CINpad);
    const int r = i - oc * 9 * CINpad;
    const int tap = r / CINpad;
    const int cin = r - tap * CINpad;
    float v = 0.f;
    if (oc < OC && cin < CIN) v = src[((size_t)oc * CIN + cin) * 9 + tap];
    const u16 h = f2bf(v);
    dh[i] = h;
    dl[i] = f2bf(v - bf2f(h));
}

__global__ void pad_bias_k(const float* __restrict__ b, float* __restrict__ bp)
{
    const int i = blockIdx.x * 256 + threadIdx.x;
    if (i < 256) bp[i] = (i < 216) ? b[i] : 0.f;
}

// ---------------------------------------------------------------------------
// MFMA 3x3 conv, stride1 pad1, f32 in/out, split-bf16 internal (3-MFMA).
// Block: 256 thr = 4 waves. Output tile 16(w) x 8(h) px, 64 oc per block.
// Wave w: all 64 oc x rows {2w, 2w+1} (2 N-tiles of 16 px).
// K staged in 32-cin chunks: LDS [hy 10][hx 18][cb*16 + hi8|lo8] u16.
// Weights: Wh/Wl [OCpad][9][CINpad] bf16 (pre-split).
// ---------------------------------------------------------------------------
template<int NCHUNK, bool RELU, bool CONCAT>
__global__ __launch_bounds__(256) void conv_mfma_k(
    const float* __restrict__ inA, const float* __restrict__ inB,
    const float* __restrict__ inC,
    const u16* __restrict__ Wh, const u16* __restrict__ Wl,
    const float* __restrict__ bias,
    float* __restrict__ out, int OCtot, int OCreal)
{
    __shared__ u16 Xs[10 * 18 * 72];          // 25,920 B
    const int CINpad = NCHUNK * 32;

    const int tile = blockIdx.x;              // 128: 16 h-tiles x 8 w-tiles
    const int h0 = (tile >> 3) * 8;
    const int w0 = (tile & 7) * 16;
    const int oc0 = blockIdx.y * 64;
    const int b = blockIdx.z;
    const int t = threadIdx.x;
    const int lane = t & 63, wv = t >> 6;
    const int fr = lane & 15, fq = lane >> 4;

    f32x4 acc[4][2];
#pragma unroll
    for (int m = 0; m < 4; ++m) {
        const float4 bv = *(const float4*)(bias + oc0 + 16 * m + 4 * fq);
#pragma unroll
        for (int n = 0; n < 2; ++n) {
            acc[m][n][0] = bv.x; acc[m][n][1] = bv.y;
            acc[m][n][2] = bv.z; acc[m][n][3] = bv.w;
        }
    }

    const u16* WhL = Wh + ((size_t)(oc0 + fr) * 9) * CINpad + 8 * fq;
    const u16* WlL = Wl + ((size_t)(oc0 + fr) * 9) * CINpad + 8 * fq;

    for (int chunk = 0; chunk < NCHUNK; ++chunk) {
        __syncthreads();
        // ---- stage 32 channels (halo 18x10) as split bf16 ----
        for (int i = t; i < 32 * 180; i += 256) {
            const int cc = i / 180;
            const int j = i - cc * 180;
            const int hy = j / 18, hx = j - hy * 18;
            const int gy = h0 + hy - 1, gx = w0 + hx - 1;
            const int ch = chunk * 32 + cc;
            float v = 0.f;
            if (gy >= 0 && gy < HH && gx >= 0 && gx < WW) {
                const int p = gy * WW + gx;
                if (CONCAT) {
                    if (ch < 64)        v = inA[((size_t)(b * 64 + ch)) * HW + p];
                    else if (ch < 128)  v = inB[((size_t)(b * 64 + ch - 64)) * HW + p];
                    else if (ch < 130)  v = inC[((size_t)(b * 2 + ch - 128)) * HW + p];
                } else {
                    v = inA[((size_t)(b * 64 + ch)) * HW + p];
                }
            }
            const u16 h = f2bf(v);
            const int base = (hy * 18 + hx) * 72 + ((cc >> 3) << 4) + (cc & 7);
            Xs[base] = h;
            Xs[base + 8] = f2bf(v - bf2f(h));
        }
        __syncthreads();

        // ---- compute: 9 taps x (2 n-tiles x 4 m-tiles x 3 split-MFMAs) ----
        const size_t koff = (size_t)chunk * 32;
#pragma unroll
        for (int tap = 0; tap < 9; ++tap) {
            const int ky = tap / 3, kx = tap % 3;
            bf16x8 Ah[4], Al[4];
#pragma unroll
            for (int m = 0; m < 4; ++m) {
                const size_t off = (size_t)(m * 144 + tap) * CINpad + koff;
                Ah[m] = ld8(WhL + off);
                Al[m] = ld8(WlL + off);
            }
#pragma unroll
            for (int n = 0; n < 2; ++n) {
                const int r = 2 * wv + n;
                const int a = ((r + ky) * 18 + fr + kx) * 72 + 16 * fq;
                const bf16x8 Bh = ld8(Xs + a);
                const bf16x8 Bl = ld8(Xs + a + 8);
#pragma unroll
                for (int m = 0; m < 4; ++m) {
                    acc[m][n] = __builtin_amdgcn_mfma_f32_16x16x32_bf16(Ah[m], Bh, acc[m][n], 0, 0, 0);
                    acc[m][n] = __builtin_amdgcn_mfma_f32_16x16x32_bf16(Ah[m], Bl, acc[m][n], 0, 0, 0);
                    acc[m][n] = __builtin_amdgcn_mfma_f32_16x16x32_bf16(Al[m], Bh, acc[m][n], 0, 0, 0);
                }
            }
        }
    }

    // ---- epilogue: lrelu + store f32 ----
#pragma unroll
    for (int m = 0; m < 4; ++m)
#pragma unroll
        for (int n = 0; n < 2; ++n) {
            const int r = 2 * wv + n;
#pragma unroll
            for (int i = 0; i < 4; ++i) {
                const int oc = oc0 + 16 * m + 4 * fq + i;
                if (oc < OCreal) {
                    float v = acc[m][n][i];
                    if (RELU) v = (v >= 0.f) ? v : 0.1f * v;
                    out[((size_t)(b * OCtot + oc)) * HW + (h0 + r) * WW + w0 + fr] = v;
                }
            }
        }
}

// ---------------------------------------------------------------------------
// x [b][64][HW] -> xq [b][16][HW] float4 channel-quads (deform gather layout)
// ---------------------------------------------------------------------------
__global__ __launch_bounds__(256) void transpose_xq_k(
    const float* __restrict__ x, float4* __restrict__ xq)
{
    const int i = blockIdx.x * 256 + threadIdx.x;
    const int pix = i & (HW - 1);
    const int q = (i >> 14) & 15;
    const int b = i >> 18;
    const float* xp = x + ((size_t)(b * 64 + q * 4)) * HW + pix;
    float4 v;
    v.x = xp[0]; v.y = xp[HW]; v.z = xp[2 * HW]; v.w = xp[3 * HW];
    xq[(size_t)(b * 16 + q) * HW + pix] = v;
}

// ---------------------------------------------------------------------------
// Deform weight [O=64][C=64][9] -> wtr[(g*9+k)*8+c][O=64]
// ---------------------------------------------------------------------------
__global__ void transpose_w_k(const float* __restrict__ wsrc, float* __restrict__ wdst)
{
    int i = blockIdx.x * 256 + threadIdx.x;
    if (i >= 64 * 64 * 9) return;
    int o  = i / 576;
    int r  = i % 576;
    int ch = r / 9;
    int k  = r % 9;
    int g = ch >> 3, c = ch & 7;
    wdst[(((g * 9 + k) * 8) + c) * 64 + o] = wsrc[i];
}

__device__ __forceinline__ unsigned pk_bf16(float lo, float hi) {
    unsigned a = __float_as_uint(lo), b = __float_as_uint(hi);
    return ((a + 0x8000u) >> 16) | ((b + 0x8000u) & 0xffff0000u);
}

// ---------------------------------------------------------------------------
// Fused deform (round-3 known-good): block = 32 pixels; gather->LDS bf16;
// contraction from LDS. One barrier, no HBM round-trip.
// ---------------------------------------------------------------------------
__global__ __launch_bounds__(256) void deform_fused_k(
    const float4* __restrict__ xq, const float* __restrict__ o4,
    const float* __restrict__ flow, const float* __restrict__ wtr,
    const float* __restrict__ bias, float* __restrict__ out)
{
    __shared__ uint4 sv[32][74];

    const int bid = blockIdx.x;
    const int b = bid >> 9;
    const int pix0 = (bid & 511) << 5;
    const int t = threadIdx.x;

    {
        const int gpx = t & 31, g = t >> 5;
        const int pix = pix0 + gpx;
        const int h = pix >> 7, w = pix & (WW - 1);
        const float fy = flow[((size_t)b * 2 + 1) * HW + pix];
        const float fx = flow[((size_t)b * 2 + 0) * HW + pix];
        const float* ob = o4 + (size_t)b * 216 * HW + pix;
        const float4* q0 = xq + (size_t)(b * 16 + g * 2) * HW;
        const float4* q1 = q0 + HW;

#pragma unroll
        for (int k = 0; k < 9; ++k) {
            const float oy = ob[(size_t)(g * 18 + k * 2) * HW];
            const float ox = ob[(size_t)(g * 18 + k * 2 + 1) * HW];
            float mm = ob[(size_t)(144 + g * 9 + k) * HW];
            mm = __builtin_amdgcn_rcpf(1.f + __expf(-mm));

            const float ay = fabsf(oy), ax = fabsf(ox);
            const float ey = __expf(-2.f * ay), ex = __expf(-2.f * ax);
            float ty = (1.f - ey) * __builtin_amdgcn_rcpf(1.f + ey);
            float tx = (1.f - ex) * __builtin_amdgcn_rcpf(1.f + ex);
            ty = copysignf(ty, oy); tx = copysignf(tx, ox);

            const float ppy = 10.f * ty + fy + (float)(h + k / 3 - 1);
            const float ppx = 10.f * tx + fx + (float)(w + k % 3 - 1);

            const float y0f = floorf(ppy), x0f = floorf(ppx);
            const float ly = ppy - y0f, lx = ppx - x0f;
            const int iy0 = (int)y0f, ix0 = (int)x0f;
            const int iy1 = iy0 + 1,  ix1 = ix0 + 1;

            const float vy0 = (iy0 >= 0 && iy0 < HH) ? 1.f : 0.f;
            const float vy1 = (iy1 >= 0 && iy1 < HH) ? 1.f : 0.f;
            const float vx0 = (ix0 >= 0 && ix0 < WW) ? 1.f : 0.f;
            const float vx1 = (ix1 >= 0 && ix1 < WW) ? 1.f : 0.f;

            const int cy0 = min(max(iy0, 0), HH - 1);
            const int cy1 = min(max(iy1, 0), HH - 1);
            const int cx0 = min(max(ix0, 0), WW - 1);
            const int cx1 = min(max(ix1, 0), WW - 1);

            const float w00 = (1.f - ly) * (1.f - lx) * vy0 * vx0 * mm;
            const float w01 = (1.f - ly) * lx         * vy0 * vx1 * mm;
            const float w10 = ly         * (1.f - lx) * vy1 * vx0 * mm;
            const float w11 = ly         * lx         * vy1 * vx1 * mm;

            const int i00 = cy0 * WW + cx0, i01 = cy0 * WW + cx1;
            const int i10 = cy1 * WW + cx0, i11 = cy1 * WW + cx1;

            const float4 a0 = q0[i00], a1 = q1[i00];
            const float4 b0 = q0[i01], b1 = q1[i01];
            const float4 c0 = q0[i10], c1 = q1[i10];
            const float4 d0 = q0[i11], d1 = q1[i11];

            float s0 = w00 * a0.x + w01 * b0.x + w10 * c0.x + w11 * d0.x;
            float s1 = w00 * a0.y + w01 * b0.y + w10 * c0.y + w11 * d0.y;
            float s2 = w00 * a0.z + w01 * b0.z + w10 * c0.z + w11 * d0.z;
            float s3 = w00 * a0.w + w01 * b0.w + w10 * c0.w + w11 * d0.w;
            float s4 = w00 * a1.x + w01 * b1.x + w10 * c1.x + w11 * d1.x;
            float s5 = w00 * a1.y + w01 * b1.y + w10 * c1.y + w11 * d1.y;
            float s6 = w00 * a1.z + w01 * b1.z + w10 * c1.z + w11 * d1.z;
            float s7 = w00 * a1.w + w01 * b1.w + w10 * c1.w + w11 * d1.w;

            uint4 P;
            P.x = pk_bf16(s0, s1);
            P.y = pk_bf16(s2, s3);
            P.z = pk_bf16(s4, s5);
            P.w = pk_bf16(s6, s7);
            sv[gpx][g * 9 + k] = P;
        }
    }
    __syncthreads();

    {
        const int px = t >> 3, oc0 = (t & 7) << 3;
        const int pix = pix0 + px;
        float acc[8];
#pragma unroll
        for (int o = 0; o < 8; ++o) acc[o] = 0.f;

        for (int g = 0; g < 8; ++g) {
#pragma unroll
            for (int k = 0; k < 9; ++k) {
                const uint4 qv = sv[px][g * 9 + k];
                float sc[8];
                sc[0] = __uint_as_float(qv.x << 16);
                sc[1] = __uint_as_float(qv.x & 0xffff0000u);
                sc[2] = __uint_as_float(qv.y << 16);
                sc[3] = __uint_as_float(qv.y & 0xffff0000u);
                sc[4] = __uint_as_float(qv.z << 16);
                sc[5] = __uint_as_float(qv.z & 0xffff0000u);
                sc[6] = __uint_as_float(qv.w << 16);
                sc[7] = __uint_as_float(qv.w & 0xffff0000u);

                const float* wp = wtr + (size_t)((g * 9 + k) * 8) * 64 + oc0;
#pragma unroll
                for (int c = 0; c < 8; ++c) {
                    const float4 wa = *(const float4*)(wp + c * 64);
                    const float4 wb = *(const float4*)(wp + c * 64 + 4);
                    acc[0] = fmaf(sc[c], wa.x, acc[0]);
                    acc[1] = fmaf(sc[c], wa.y, acc[1]);
                    acc[2] = fmaf(sc[c], wa.z, acc[2]);
                    acc[3] = fmaf(sc[c], wa.w, acc[3]);
                    acc[4] = fmaf(sc[c], wb.x, acc[4]);
                    acc[5] = fmaf(sc[c], wb.y, acc[5]);
                    acc[6] = fmaf(sc[c], wb.z, acc[6]);
                    acc[7] = fmaf(sc[c], wb.w, acc[7]);
                }
            }
        }

#pragma unroll
        for (int o = 0; o < 8; ++o)
            out[((size_t)b * 64 + oc0 + o) * HW + pix] = acc[o] + bias[oc0 + o];
    }
}

// ---------------------------------------------------------------------------
extern "C" void kernel_launch(void* const* d_in, const int* in_sizes, int n_in,
                              void* d_out, int out_size, void* d_ws, size_t ws_size,
                              hipStream_t stream)
{
    const float* x     = (const float*)d_in[0];
    const float* xw    = (const float*)d_in[1];
    const float* xc    = (const float*)d_in[2];
    const float* flow  = (const float*)d_in[3];
    const float* w1    = (const float*)d_in[4];
    const float* b1    = (const float*)d_in[5];
    const float* w2    = (const float*)d_in[6];
    const float* b2    = (const float*)d_in[7];
    const float* w3    = (const float*)d_in[8];
    const float* b3    = (const float*)d_in[9];
    const float* w4    = (const float*)d_in[10];
    const float* b4    = (const float*)d_in[11];
    const float* wt    = (const float*)d_in[12];
    const float* bias  = (const float*)d_in[13];
    float* out = (float*)d_out;

    char* ws = (char*)d_ws;
    // ws layout (~91.6 MB):
    //   o1   [0, 16.8M)           conv1 out, later conv3 out
    //   o2   [16.8M, 33.6M)       conv2 out, later xq
    //   o4   [33.6M, 90.2M)       conv4 out
    //   wtr  @90177536 (147456)   transposed deform weight
    //   W1h/W1l @90324992/90509312 (184320 ea)
    //   W2h/W2l @90693632/90767360 (73728 ea)
    //   W3h/W3l @90841088/90914816 (73728 ea)
    //   W4h/W4l @90988544/91283456 (294912 ea)
    //   b4p  @91578368 (1024)
    float* o1  = (float*)(ws);
    float* o2  = (float*)(ws + 16777216);
    float* o4  = (float*)(ws + 33554432);
    float* wtr = (float*)(ws + 90177536);
    u16* W1h = (u16*)(ws + 90324992);
    u16* W1l = (u16*)(ws + 90509312);
    u16* W2h = (u16*)(ws + 90693632);
    u16* W2l = (u16*)(ws + 90767360);
    u16* W3h = (u16*)(ws + 90841088);
    u16* W3l = (u16*)(ws + 90914816);
    u16* W4h = (u16*)(ws + 90988544);
    u16* W4l = (u16*)(ws + 91283456);
    float* b4p = (float*)(ws + 91578368);
    float4* xq = (float4*)o2;

    const dim3 blk(256);

    // weight prep
    split_w_k<<<dim3((64 * 9 * 160 + 255) / 256), blk, 0, stream>>>(w1, W1h, W1l, 64, 64, 130, 160);
    split_w_k<<<dim3((64 * 9 * 64 + 255) / 256), blk, 0, stream>>>(w2, W2h, W2l, 64, 64, 64, 64);
    split_w_k<<<dim3((64 * 9 * 64 + 255) / 256), blk, 0, stream>>>(w3, W3h, W3l, 64, 64, 64, 64);
    split_w_k<<<dim3((256 * 9 * 64 + 255) / 256), blk, 0, stream>>>(w4, W4h, W4l, 216, 256, 64, 64);
    pad_bias_k<<<dim3(1), blk, 0, stream>>>(b4, b4p);
    transpose_w_k<<<dim3((36864 + 255) / 256), blk, 0, stream>>>(wt, wtr);

    // conv1: 130 -> 64, lrelu (concat input), 5 K-chunks (cin padded to 160)
    conv_mfma_k<5, true, true><<<dim3(128, 1, BB), blk, 0, stream>>>(
        xw, xc, flow, W1h, W1l, b1, o1, 64, 64);
    // conv2: 64 -> 64, lrelu
    conv_mfma_k<2, true, false><<<dim3(128, 1, BB), blk, 0, stream>>>(
        o1, nullptr, nullptr, W2h, W2l, b2, o2, 64, 64);
    // conv3: 64 -> 64, lrelu (into o1)
    conv_mfma_k<2, true, false><<<dim3(128, 1, BB), blk, 0, stream>>>(
        o2, nullptr, nullptr, W3h, W3l, b3, o1, 64, 64);
    // x -> channel-quad layout (slot of o2 is dead after conv3)
    transpose_xq_k<<<dim3(BB * 16 * HW / 256), blk, 0, stream>>>(x, xq);
    // conv4: 64 -> 216 (oc padded to 256, stores guarded), no act
    conv_mfma_k<2, false, false><<<dim3(128, 4, BB), blk, 0, stream>>>(
        o1, nullptr, nullptr, W4h, W4l, b4p, o4, 216, 216);

    deform_fused_k<<<dim3(BB * HW / 32), blk, 0, stream>>>(
        xq, o4, flow, wtr, bias, out);
}

// Round 5
// 693.291 us; speedup vs baseline: 2.6527x; 1.0182x over previous
//
#include <hip/hip_runtime.h>
#include <math.h>

#define HH 128
#define WW 128
#define BB 4
#define HW (HH*WW)

typedef unsigned short u16;
typedef unsigned int u32;
typedef __bf16 bf16x8 __attribute__((ext_vector_type(8)));
typedef float f32x4 __attribute__((ext_vector_type(4)));

__device__ __forceinline__ u16 f2bf(float x) {
    u32 u = __float_as_uint(x);
    return (u16)((u + 0x7fffu + ((u >> 16) & 1u)) >> 16);
}
__device__ __forceinline__ float bf2f(u16 h) {
    return __uint_as_float(((u32)h) << 16);
}
__device__ __forceinline__ bf16x8 ld8(const u16* p) {
    union { uint4 u; bf16x8 v; } c;
    c.u = *(const uint4*)p;
    return c.v;
}
__device__ __forceinline__ bf16x8 cvt8(uint4 u) {
    union { uint4 u; bf16x8 v; } c;
    c.u = u;
    return c.v;
}

// ---------------------------------------------------------------------------
// Weight split-prep: src [OC][CIN][3][3] f32 -> dh/dl [OCpad][9][CINpad] bf16
// ---------------------------------------------------------------------------
__global__ void split_w_k(const float* __restrict__ src, u16* __restrict__ dh,
                          u16* __restrict__ dl, int OC, int OCpad, int CIN, int CINpad)
{
    const int i = blockIdx.x * 256 + threadIdx.x;
    const int tot = OCpad * 9 * CINpad;
    if (i >= tot) return;
    const int oc = i / (9 * CINpad);
    const int r = i - oc * 9 * CINpad;
    const int tap = r / CINpad;
    const int cin = r - tap * CINpad;
    float v = 0.f;
    if (oc < OC && cin < CIN) v = src[((size_t)oc * CIN + cin) * 9 + tap];
    const u16 h = f2bf(v);
    dh[i] = h;
    dl[i] = f2bf(v - bf2f(h));
}

__global__ void pad_bias_k(const float* __restrict__ b, float* __restrict__ bp)
{
    const int i = blockIdx.x * 256 + threadIdx.x;
    if (i < 256) bp[i] = (i < 216) ? b[i] : 0.f;
}

// ---------------------------------------------------------------------------
// Deform weight [O=64][C=64][3][3] -> bf16 A-fragments for 16x16x32 MFMA:
// Apack u16[kk(18)][fq(4)][m(4)][fr(16)][jj(8)]  (oc = m*16+fr, k = kk*32+fq*8+jj)
// k index j maps: tap = j>>3, c = j&7, group g = tap/9, ktap = tap%9, ch = g*8+c
// ---------------------------------------------------------------------------
__global__ void pack_dw_k(const float* __restrict__ wt, u16* __restrict__ Apack)
{
    const int i = blockIdx.x * 256 + threadIdx.x;   // 36864 = 18*4*4*16*8
    if (i >= 36864) return;
    const int jj = i & 7;
    const int fr = (i >> 3) & 15;
    const int m  = (i >> 7) & 3;
    const int fq = (i >> 9) & 3;
    const int kk = i >> 11;
    const int oc = m * 16 + fr;
    const int j  = kk * 32 + fq * 8 + jj;           // < 576 always
    const int tap = j >> 3, c = j & 7;
    const int g = tap / 9, kt = tap - g * 9;
    const int ch = g * 8 + c;
    Apack[i] = f2bf(wt[((size_t)oc * 64 + ch) * 9 + kt]);
}

// ---------------------------------------------------------------------------
// MFMA 3x3 conv, stride1 pad1, f32 in/out, split-bf16 internal (3-MFMA).
// Block: 256 thr = 4 waves. Output tile 16(w) x 4(h); wave wv = row h0+wv.
// 64 oc per block (blockIdx.y). K staged in 32-cin chunks:
// LDS [hy 6][hx 18][cb*16 + hi8|lo8] u16. Weights pre-split [OCpad][9][CINpad].
// ---------------------------------------------------------------------------
template<int NCHUNK, bool RELU, bool CONCAT>
__global__ __launch_bounds__(256) void conv_mfma_k(
    const float* __restrict__ inA, const float* __restrict__ inB,
    const float* __restrict__ inC,
    const u16* __restrict__ Wh, const u16* __restrict__ Wl,
    const float* __restrict__ bias,
    float* __restrict__ out, int OCtot, int OCreal)
{
    __shared__ u16 Xs[6 * 18 * 72];           // 15,552 B
    const int CINpad = NCHUNK * 32;

    const int tile = blockIdx.x;              // 256: 32 h-tiles x 8 w-tiles
    const int h0 = (tile >> 3) * 4;
    const int w0 = (tile & 7) * 16;
    const int oc0 = blockIdx.y * 64;
    const int b = blockIdx.z;
    const int t = threadIdx.x;
    const int lane = t & 63, wv = t >> 6;
    const int fr = lane & 15, fq = lane >> 4;

    f32x4 acc[4];
#pragma unroll
    for (int m = 0; m < 4; ++m) {
        const float4 bv = *(const float4*)(bias + oc0 + 16 * m + 4 * fq);
        acc[m][0] = bv.x; acc[m][1] = bv.y; acc[m][2] = bv.z; acc[m][3] = bv.w;
    }

    const u16* WhL = Wh + ((size_t)(oc0 + fr) * 9) * CINpad + 8 * fq;
    const u16* WlL = Wl + ((size_t)(oc0 + fr) * 9) * CINpad + 8 * fq;

    for (int chunk = 0; chunk < NCHUNK; ++chunk) {
        __syncthreads();
        // ---- stage 32 channels (halo 18x6) as split bf16 ----
        for (int i = t; i < 32 * 108; i += 256) {
            const int cc = i / 108;
            const int j = i - cc * 108;
            const int hy = j / 18, hx = j - hy * 18;
            const int gy = h0 + hy - 1, gx = w0 + hx - 1;
            const int ch = chunk * 32 + cc;
            float v = 0.f;
            if (gy >= 0 && gy < HH && gx >= 0 && gx < WW) {
                const int p = gy * WW + gx;
                if (CONCAT) {
                    if (ch < 64)        v = inA[((size_t)(b * 64 + ch)) * HW + p];
                    else if (ch < 128)  v = inB[((size_t)(b * 64 + ch - 64)) * HW + p];
                    else if (ch < 130)  v = inC[((size_t)(b * 2 + ch - 128)) * HW + p];
                } else {
                    v = inA[((size_t)(b * 64 + ch)) * HW + p];
                }
            }
            const u16 h = f2bf(v);
            const int base = (hy * 18 + hx) * 72 + ((cc >> 3) << 4) + (cc & 7);
            Xs[base] = h;
            Xs[base + 8] = f2bf(v - bf2f(h));
        }
        __syncthreads();

        const size_t koff = (size_t)chunk * 32;
#pragma unroll
        for (int tap = 0; tap < 9; ++tap) {
            const int ky = tap / 3, kx = tap % 3;
            bf16x8 Ah[4], Al[4];
#pragma unroll
            for (int m = 0; m < 4; ++m) {
                const size_t off = (size_t)(m * 144 + tap) * CINpad + koff;
                Ah[m] = ld8(WhL + off);
                Al[m] = ld8(WlL + off);
            }
            const int a = ((wv + ky) * 18 + fr + kx) * 72 + 16 * fq;
            const bf16x8 Bh = ld8(Xs + a);
            const bf16x8 Bl = ld8(Xs + a + 8);
#pragma unroll
            for (int m = 0; m < 4; ++m) {
                acc[m] = __builtin_amdgcn_mfma_f32_16x16x32_bf16(Ah[m], Bh, acc[m], 0, 0, 0);
                acc[m] = __builtin_amdgcn_mfma_f32_16x16x32_bf16(Ah[m], Bl, acc[m], 0, 0, 0);
                acc[m] = __builtin_amdgcn_mfma_f32_16x16x32_bf16(Al[m], Bh, acc[m], 0, 0, 0);
            }
        }
    }

#pragma unroll
    for (int m = 0; m < 4; ++m)
#pragma unroll
        for (int i = 0; i < 4; ++i) {
            const int oc = oc0 + 16 * m + 4 * fq + i;
            if (oc < OCreal) {
                float v = acc[m][i];
                if (RELU) v = (v >= 0.f) ? v : 0.1f * v;
                out[((size_t)(b * OCtot + oc)) * HW + (h0 + wv) * WW + w0 + fr] = v;
            }
        }
}

// ---------------------------------------------------------------------------
// x [b][64][HW] -> xq [b][16][HW] float4 channel-quads (deform gather layout)
// ---------------------------------------------------------------------------
__global__ __launch_bounds__(256) void transpose_xq_k(
    const float* __restrict__ x, float4* __restrict__ xq)
{
    const int i = blockIdx.x * 256 + threadIdx.x;
    const int pix = i & (HW - 1);
    const int q = (i >> 14) & 15;
    const int b = i >> 18;
    const float* xp = x + ((size_t)(b * 64 + q * 4)) * HW + pix;
    float4 v;
    v.x = xp[0]; v.y = xp[HW]; v.z = xp[2 * HW]; v.w = xp[3 * HW];
    xq[(size_t)(b * 16 + q) * HW + pix] = v;
}

__device__ __forceinline__ unsigned pk_bf16(float lo, float hi) {
    unsigned a = __float_as_uint(lo), b = __float_as_uint(hi);
    return ((a + 0x8000u) >> 16) | ((b + 0x8000u) & 0xffff0000u);
}

// ---------------------------------------------------------------------------
// Fused deform. Block = 32 px, 256 thr.
// Phase 1: thread=(px,g): offsets/mask -> 9 taps bilinear -> bf16 into LDS
//          sv[px][j=576], row stride 584 u16 (1168 B, conflict-padded).
// Phase 2: MFMA contraction: A = Apack (oc x k), B = sv (k x px).
//          Wave wv: M-tile wv (16 oc), both N-tiles (2 x 16 px), K = 18 chunks.
// ---------------------------------------------------------------------------
__global__ __launch_bounds__(256, 4) void deform_fused_k(
    const float4* __restrict__ xq, const float* __restrict__ o4,
    const float* __restrict__ flow, const uint4* __restrict__ Apack,
    const float* __restrict__ bias, float* __restrict__ out)
{
    __shared__ u16 sv[32 * 584];   // 37,376 B

    const int bid = blockIdx.x;    // 2048
    const int b = bid >> 9;
    const int pix0 = (bid & 511) << 5;
    const int t = threadIdx.x;

    // ---------------- phase 1: gather (px = t&31, g = t>>5) ----------------
    {
        const int gpx = t & 31, g = t >> 5;
        const int pix = pix0 + gpx;
        const int h = pix >> 7, w = pix & (WW - 1);
        const float fy = flow[((size_t)b * 2 + 1) * HW + pix];
        const float fx = flow[((size_t)b * 2 + 0) * HW + pix];
        const float* ob = o4 + (size_t)b * 216 * HW + pix;
        const float4* q0 = xq + (size_t)(b * 16 + g * 2) * HW;
        const float4* q1 = q0 + HW;

        int   code[9];
        float w00[9], w01[9], w10[9], w11[9];

#pragma unroll
        for (int k = 0; k < 9; ++k) {
            const float oy = ob[(size_t)(g * 18 + k * 2) * HW];
            const float ox = ob[(size_t)(g * 18 + k * 2 + 1) * HW];
            float mm = ob[(size_t)(144 + g * 9 + k) * HW];
            mm = __builtin_amdgcn_rcpf(1.f + __expf(-mm));

            const float ay = fabsf(oy), ax = fabsf(ox);
            const float ey = __expf(-2.f * ay), ex = __expf(-2.f * ax);
            float ty = (1.f - ey) * __builtin_amdgcn_rcpf(1.f + ey);
            float tx = (1.f - ex) * __builtin_amdgcn_rcpf(1.f + ex);
            ty = copysignf(ty, oy); tx = copysignf(tx, ox);

            const float ppy = 10.f * ty + fy + (float)(h + k / 3 - 1);
            const float ppx = 10.f * tx + fx + (float)(w + k % 3 - 1);

            const float y0f = floorf(ppy), x0f = floorf(ppx);
            const float ly = ppy - y0f, lx = ppx - x0f;
            const int iy0 = (int)y0f, ix0 = (int)x0f;
            const int iy1 = iy0 + 1,  ix1 = ix0 + 1;

            const float vy0 = (iy0 >= 0 && iy0 < HH) ? 1.f : 0.f;
            const float vy1 = (iy1 >= 0 && iy1 < HH) ? 1.f : 0.f;
            const float vx0 = (ix0 >= 0 && ix0 < WW) ? 1.f : 0.f;
            const float vx1 = (ix1 >= 0 && ix1 < WW) ? 1.f : 0.f;

            const int cy0 = min(max(iy0, 0), HH - 1);
            const int cy1 = min(max(iy1, 0), HH - 1);
            const int cx0 = min(max(ix0, 0), WW - 1);
            const int cx1 = min(max(ix1, 0), WW - 1);

            w00[k] = (1.f - ly) * (1.f - lx) * vy0 * vx0 * mm;
            w01[k] = (1.f - ly) * lx         * vy0 * vx1 * mm;
            w10[k] = ly         * (1.f - lx) * vy1 * vx0 * mm;
            w11[k] = ly         * lx         * vy1 * vx1 * mm;

            code[k] = (cy0 * WW + cx0) | ((cx1 - cx0) << 14) | ((cy1 - cy0) << 15);
        }

        u16* svp = sv + gpx * 584 + g * 72;   // j base = (g*9+k)*8
#pragma unroll
        for (int k = 0; k < 9; ++k) {
            const int i00 = code[k] & 16383;
            const int i01 = i00 + ((code[k] >> 14) & 1);
            const int i10 = i00 + (((code[k] >> 15) & 1) << 7);
            const int i11 = i10 + ((code[k] >> 14) & 1);

            const float4 a0 = q0[i00], a1 = q1[i00];
            const float4 b0 = q0[i01], b1 = q1[i01];
            const float4 c0 = q0[i10], c1 = q1[i10];
            const float4 d0 = q0[i11], d1 = q1[i11];
            const float W00 = w00[k], W01 = w01[k], W10 = w10[k], W11 = w11[k];

            float s0 = W00 * a0.x + W01 * b0.x + W10 * c0.x + W11 * d0.x;
            float s1 = W00 * a0.y + W01 * b0.y + W10 * c0.y + W11 * d0.y;
            float s2 = W00 * a0.z + W01 * b0.z + W10 * c0.z + W11 * d0.z;
            float s3 = W00 * a0.w + W01 * b0.w + W10 * c0.w + W11 * d0.w;
            float s4 = W00 * a1.x + W01 * b1.x + W10 * c1.x + W11 * d1.x;
            float s5 = W00 * a1.y + W01 * b1.y + W10 * c1.y + W11 * d1.y;
            float s6 = W00 * a1.z + W01 * b1.z + W10 * c1.z + W11 * d1.z;
            float s7 = W00 * a1.w + W01 * b1.w + W10 * c1.w + W11 * d1.w;

            uint4 P;
            P.x = pk_bf16(s0, s1);
            P.y = pk_bf16(s2, s3);
            P.z = pk_bf16(s4, s5);
            P.w = pk_bf16(s6, s7);
            *(uint4*)(svp + (size_t)k * 8) = P;
        }
    }
    __syncthreads();

    // ---------------- phase 2: MFMA (wave wv = M-tile) ---------------------
    {
        const int lane = t & 63, wv = t >> 6;
        const int fr = lane & 15, fq = lane >> 4;

        f32x4 acc[2];
#pragma unroll
        for (int n = 0; n < 2; ++n) { acc[n][0] = 0.f; acc[n][1] = 0.f; acc[n][2] = 0.f; acc[n][3] = 0.f; }

#pragma unroll
        for (int kk = 0; kk < 18; ++kk) {
            const bf16x8 A = cvt8(Apack[((kk * 4 + fq) * 4 + wv) * 16 + fr]);
#pragma unroll
            for (int n = 0; n < 2; ++n) {
                const bf16x8 Bf = ld8(sv + (size_t)(n * 16 + fr) * 584 + kk * 32 + fq * 8);
                acc[n] = __builtin_amdgcn_mfma_f32_16x16x32_bf16(A, Bf, acc[n], 0, 0, 0);
            }
        }

        const float4 bv = *(const float4*)(bias + wv * 16 + 4 * fq);
        const float bb[4] = { bv.x, bv.y, bv.z, bv.w };
#pragma unroll
        for (int n = 0; n < 2; ++n) {
            const int pix = pix0 + n * 16 + fr;
#pragma unroll
            for (int i = 0; i < 4; ++i) {
                const int oc = wv * 16 + 4 * fq + i;
                out[((size_t)b * 64 + oc) * HW + pix] = acc[n][i] + bb[i];
            }
        }
    }
}

// ---------------------------------------------------------------------------
extern "C" void kernel_launch(void* const* d_in, const int* in_sizes, int n_in,
                              void* d_out, int out_size, void* d_ws, size_t ws_size,
                              hipStream_t stream)
{
    const float* x     = (const float*)d_in[0];
    const float* xw    = (const float*)d_in[1];
    const float* xc    = (const float*)d_in[2];
    const float* flow  = (const float*)d_in[3];
    const float* w1    = (const float*)d_in[4];
    const float* b1    = (const float*)d_in[5];
    const float* w2    = (const float*)d_in[6];
    const float* b2    = (const float*)d_in[7];
    const float* w3    = (const float*)d_in[8];
    const float* b3    = (const float*)d_in[9];
    const float* w4    = (const float*)d_in[10];
    const float* b4    = (const float*)d_in[11];
    const float* wt    = (const float*)d_in[12];
    const float* bias  = (const float*)d_in[13];
    float* out = (float*)d_out;

    char* ws = (char*)d_ws;
    // ws layout (~91.6 MB):
    //   o1   [0, 16.8M)           conv1 out, later conv3 out
    //   o2   [16.8M, 33.6M)       conv2 out, later xq
    //   o4   [33.6M, 90.2M)       conv4 out
    //   Apack @90177536 (73728)   deform weight A-fragments (bf16)
    //   W1h/W1l @90324992/90509312 (184320 ea)
    //   W2h/W2l @90693632/90767360 (73728 ea)
    //   W3h/W3l @90841088/90914816 (73728 ea)
    //   W4h/W4l @90988544/91283456 (294912 ea)
    //   b4p  @91578368 (1024)
    float* o1  = (float*)(ws);
    float* o2  = (float*)(ws + 16777216);
    float* o4  = (float*)(ws + 33554432);
    u16* Apack = (u16*)(ws + 90177536);
    u16* W1h = (u16*)(ws + 90324992);
    u16* W1l = (u16*)(ws + 90509312);
    u16* W2h = (u16*)(ws + 90693632);
    u16* W2l = (u16*)(ws + 90767360);
    u16* W3h = (u16*)(ws + 90841088);
    u16* W3l = (u16*)(ws + 90914816);
    u16* W4h = (u16*)(ws + 90988544);
    u16* W4l = (u16*)(ws + 91283456);
    float* b4p = (float*)(ws + 91578368);
    float4* xq = (float4*)o2;

    const dim3 blk(256);

    // weight prep
    split_w_k<<<dim3((64 * 9 * 160 + 255) / 256), blk, 0, stream>>>(w1, W1h, W1l, 64, 64, 130, 160);
    split_w_k<<<dim3((64 * 9 * 64 + 255) / 256), blk, 0, stream>>>(w2, W2h, W2l, 64, 64, 64, 64);
    split_w_k<<<dim3((64 * 9 * 64 + 255) / 256), blk, 0, stream>>>(w3, W3h, W3l, 64, 64, 64, 64);
    split_w_k<<<dim3((256 * 9 * 64 + 255) / 256), blk, 0, stream>>>(w4, W4h, W4l, 216, 256, 64, 64);
    pad_bias_k<<<dim3(1), blk, 0, stream>>>(b4, b4p);
    pack_dw_k<<<dim3(144), blk, 0, stream>>>(wt, Apack);

    // conv1: 130 -> 64, lrelu (concat input), cin padded to 160
    conv_mfma_k<5, true, true><<<dim3(256, 1, BB), blk, 0, stream>>>(
        xw, xc, flow, W1h, W1l, b1, o1, 64, 64);
    // conv2: 64 -> 64, lrelu
    conv_mfma_k<2, true, false><<<dim3(256, 1, BB), blk, 0, stream>>>(
        o1, nullptr, nullptr, W2h, W2l, b2, o2, 64, 64);
    // conv3: 64 -> 64, lrelu (into o1)
    conv_mfma_k<2, true, false><<<dim3(256, 1, BB), blk, 0, stream>>>(
        o2, nullptr, nullptr, W3h, W3l, b3, o1, 64, 64);
    // x -> channel-quad layout (o2 slot dead after conv3)
    transpose_xq_k<<<dim3(BB * 16 * HW / 256), blk, 0, stream>>>(x, xq);
    // conv4: 64 -> 216 (oc padded to 256, stores guarded), no act
    conv_mfma_k<2, false, false><<<dim3(256, 4, BB), blk, 0, stream>>>(
        o1, nullptr, nullptr, W4h, W4l, b4p, o4, 216, 216);

    deform_fused_k<<<dim3(BB * HW / 32), blk, 0, stream>>>(
        xq, o4, flow, (const uint4*)Apack, bias, out);
}

// Round 6
// 525.462 us; speedup vs baseline: 3.4999x; 1.3194x over previous
//
#include <hip/hip_runtime.h>
#include <math.h>

#define HH 128
#define WW 128
#define BB 4
#define HW (HH*WW)

typedef unsigned short u16;
typedef unsigned int u32;
typedef __bf16 bf16x8 __attribute__((ext_vector_type(8)));
typedef float f32x4 __attribute__((ext_vector_type(4)));

__device__ __forceinline__ u16 f2bf(float x) {
    u32 u = __float_as_uint(x);
    return (u16)((u + 0x7fffu + ((u >> 16) & 1u)) >> 16);
}
__device__ __forceinline__ float bf2f(u16 h) {
    return __uint_as_float(((u32)h) << 16);
}
__device__ __forceinline__ bf16x8 ld8(const u16* p) {
    union { uint4 u; bf16x8 v; } c;
    c.u = *(const uint4*)p;
    return c.v;
}
__device__ __forceinline__ bf16x8 cvt8(uint4 u) {
    union { uint4 u; bf16x8 v; } c;
    c.u = u;
    return c.v;
}

// ---------------------------------------------------------------------------
// Weight split-prep: src [OC][CIN][3][3] f32 -> dh/dl [OCpad][9][CINpad] bf16
// ---------------------------------------------------------------------------
__global__ void split_w_k(const float* __restrict__ src, u16* __restrict__ dh,
                          u16* __restrict__ dl, int OC, int OCpad, int CIN, int CINpad)
{
    const int i = blockIdx.x * 256 + threadIdx.x;
    const int tot = OCpad * 9 * CINpad;
    if (i >= tot) return;
    const int oc = i / (9 * CINpad);
    const int r = i - oc * 9 * CINpad;
    const int tap = r / CINpad;
    const int cin = r - tap * CINpad;
    float v = 0.f;
    if (oc < OC && cin < CIN) v = src[((size_t)oc * CIN + cin) * 9 + tap];
    const u16 h = f2bf(v);
    dh[i] = h;
    dl[i] = f2bf(v - bf2f(h));
}

__global__ void pad_bias_k(const float* __restrict__ b, float* __restrict__ bp)
{
    const int i = blockIdx.x * 256 + threadIdx.x;
    if (i < 256) bp[i] = (i < 216) ? b[i] : 0.f;
}

// ---------------------------------------------------------------------------
// Deform weight [O=64][C=64][3][3] -> bf16 A-fragments for 16x16x32 MFMA:
// Apack u16[kk(18)][fq(4)][m(4)][fr(16)][jj(8)]
// ---------------------------------------------------------------------------
__global__ void pack_dw_k(const float* __restrict__ wt, u16* __restrict__ Apack)
{
    const int i = blockIdx.x * 256 + threadIdx.x;   // 36864
    if (i >= 36864) return;
    const int jj = i & 7;
    const int fr = (i >> 3) & 15;
    const int m  = (i >> 7) & 3;
    const int fq = (i >> 9) & 3;
    const int kk = i >> 11;
    const int oc = m * 16 + fr;
    const int j  = kk * 32 + fq * 8 + jj;
    const int tap = j >> 3, c = j & 7;
    const int g = tap / 9, kt = tap - g * 9;
    const int ch = g * 8 + c;
    Apack[i] = f2bf(wt[((size_t)oc * 64 + ch) * 9 + kt]);
}

// ---------------------------------------------------------------------------
// Pack NCHW f32 (or concat of 3 sources) into split-bf16 records:
// dst[b*HW+px][CREC*2 u16], ch c at idx (c>>5)*64 + ((c>>3)&3)*16 + (c&7),
// lo at +8. CONCAT: c<64 A, <128 B2, <130 C3, else 0 (CREC=192 pad).
// ---------------------------------------------------------------------------
template<int CREC, bool CONCAT>
__global__ __launch_bounds__(256) void pack_x_k(
    const float* __restrict__ A, const float* __restrict__ B2,
    const float* __restrict__ C3, u16* __restrict__ dst)
{
    const int i = blockIdx.x * 256 + threadIdx.x;   // b*HW + px
    const int b = i >> 14;
    const int px = i & 16383;
    u16* rec = dst + (size_t)i * (CREC * 2);

#pragma unroll
    for (int g = 0; g < CREC / 32; ++g) {
#pragma unroll
        for (int cb = 0; cb < 4; ++cb) {
            u32 hwv[4], lwv[4];
#pragma unroll
            for (int p = 0; p < 4; ++p) {
                float v[2];
#pragma unroll
                for (int e = 0; e < 2; ++e) {
                    const int c = g * 32 + cb * 8 + p * 2 + e;
                    float vv;
                    if (CONCAT) {
                        if (c < 64)       vv = A[((size_t)(b * 64 + c)) * HW + px];
                        else if (c < 128) vv = B2[((size_t)(b * 64 + c - 64)) * HW + px];
                        else if (c < 130) vv = C3[((size_t)(b * 2 + c - 128)) * HW + px];
                        else              vv = 0.f;
                    } else {
                        vv = A[((size_t)(b * CREC + c)) * HW + px];
                    }
                    v[e] = vv;
                }
                const u16 h0 = f2bf(v[0]), h1 = f2bf(v[1]);
                const u16 l0 = f2bf(v[0] - bf2f(h0)), l1 = f2bf(v[1] - bf2f(h1));
                hwv[p] = (u32)h0 | ((u32)h1 << 16);
                lwv[p] = (u32)l0 | ((u32)l1 << 16);
            }
            uint4 H; H.x = hwv[0]; H.y = hwv[1]; H.z = hwv[2]; H.w = hwv[3];
            uint4 L; L.x = lwv[0]; L.y = lwv[1]; L.z = lwv[2]; L.w = lwv[3];
            *(uint4*)(rec + g * 64 + cb * 16)     = H;
            *(uint4*)(rec + g * 64 + cb * 16 + 8) = L;
        }
    }
}

// ---------------------------------------------------------------------------
// MFMA 3x3 conv on packed split-bf16 input. Block: 4 waves, tile 16(w)x8(h),
// 64 oc; wave wv owns rows {2wv, 2wv+1}. Per 64-ch chunk: stage 180 px x 256B
// records into LDS (uint4 copies, stride 272B bank-clean), then 9 taps x 2 kg
// x 3 split-MFMAs. Output f32 NCHW (+lrelu).
// ---------------------------------------------------------------------------
template<int NCHUNK, bool RELU>
__global__ __launch_bounds__(256) void conv_pk_k(
    const u16* __restrict__ Xp, const u16* __restrict__ Wh, const u16* __restrict__ Wl,
    const float* __restrict__ bias, float* __restrict__ out, int OCtot, int OCreal)
{
    __shared__ u16 Xs[180 * 136];             // 48,960 B
    const int CINpad = NCHUNK * 64;

    const int tile = blockIdx.x;              // 128 = 16 h-tiles x 8 w-tiles
    const int h0 = (tile >> 3) * 8;
    const int w0 = (tile & 7) * 16;
    const int oc0 = blockIdx.y * 64;
    const int b = blockIdx.z;
    const int t = threadIdx.x;
    const int lane = t & 63, wv = t >> 6;
    const int fr = lane & 15, fq = lane >> 4;

    f32x4 acc[4][2];
#pragma unroll
    for (int m = 0; m < 4; ++m) {
        const float4 bv = *(const float4*)(bias + oc0 + 16 * m + 4 * fq);
#pragma unroll
        for (int n = 0; n < 2; ++n) {
            acc[m][n][0] = bv.x; acc[m][n][1] = bv.y;
            acc[m][n][2] = bv.z; acc[m][n][3] = bv.w;
        }
    }

    const u16* WhL = Wh + ((size_t)(oc0 + fr) * 9) * CINpad + 8 * fq;
    const u16* WlL = Wl + ((size_t)(oc0 + fr) * 9) * CINpad + 8 * fq;

    for (int chunk = 0; chunk < NCHUNK; ++chunk) {
        __syncthreads();
        // ---- stage: 180 px x 16 uint4 (pure copies, zero-fill halo) ----
        for (int s = t; s < 2880; s += 256) {
            const int px = s >> 4, o16 = s & 15;
            const int hy = px / 18, hx = px - hy * 18;
            const int gy = h0 + hy - 1, gx = w0 + hx - 1;
            uint4 v; v.x = 0; v.y = 0; v.z = 0; v.w = 0;
            if (gy >= 0 && gy < HH && gx >= 0 && gx < WW)
                v = *(const uint4*)(Xp + ((size_t)(b * HW + gy * WW + gx)) * (NCHUNK * 128)
                                       + chunk * 128 + o16 * 8);
            *(uint4*)(Xs + px * 136 + o16 * 8) = v;
        }
        __syncthreads();

#pragma unroll
        for (int tap = 0; tap < 9; ++tap) {
            const int ky = tap / 3, kx = tap % 3;
#pragma unroll
            for (int kg = 0; kg < 2; ++kg) {
                bf16x8 Ah[4], Al[4];
#pragma unroll
                for (int m = 0; m < 4; ++m) {
                    const size_t off = (size_t)(m * 144 + tap) * CINpad + chunk * 64 + kg * 32;
                    Ah[m] = ld8(WhL + off);
                    Al[m] = ld8(WlL + off);
                }
#pragma unroll
                for (int n = 0; n < 2; ++n) {
                    const int r = 2 * wv + n;
                    const int hp = (r + ky) * 18 + fr + kx;
                    const bf16x8 Bh = ld8(Xs + hp * 136 + kg * 64 + fq * 16);
                    const bf16x8 Bl = ld8(Xs + hp * 136 + kg * 64 + fq * 16 + 8);
#pragma unroll
                    for (int m = 0; m < 4; ++m) {
                        acc[m][n] = __builtin_amdgcn_mfma_f32_16x16x32_bf16(Ah[m], Bh, acc[m][n], 0, 0, 0);
                        acc[m][n] = __builtin_amdgcn_mfma_f32_16x16x32_bf16(Ah[m], Bl, acc[m][n], 0, 0, 0);
                        acc[m][n] = __builtin_amdgcn_mfma_f32_16x16x32_bf16(Al[m], Bh, acc[m][n], 0, 0, 0);
                    }
                }
            }
        }
    }

#pragma unroll
    for (int m = 0; m < 4; ++m)
#pragma unroll
        for (int n = 0; n < 2; ++n) {
            const int r = 2 * wv + n;
#pragma unroll
            for (int i = 0; i < 4; ++i) {
                const int oc = oc0 + 16 * m + 4 * fq + i;
                if (oc < OCreal) {
                    float v = acc[m][n][i];
                    if (RELU) v = (v >= 0.f) ? v : 0.1f * v;
                    out[((size_t)(b * OCtot + oc)) * HW + (h0 + r) * WW + w0 + fr] = v;
                }
            }
        }
}

// ---------------------------------------------------------------------------
// x [b][64][HW] -> xq [b][16][HW] float4 channel-quads (deform gather layout)
// ---------------------------------------------------------------------------
__global__ __launch_bounds__(256) void transpose_xq_k(
    const float* __restrict__ x, float4* __restrict__ xq)
{
    const int i = blockIdx.x * 256 + threadIdx.x;
    const int pix = i & (HW - 1);
    const int q = (i >> 14) & 15;
    const int b = i >> 18;
    const float* xp = x + ((size_t)(b * 64 + q * 4)) * HW + pix;
    float4 v;
    v.x = xp[0]; v.y = xp[HW]; v.z = xp[2 * HW]; v.w = xp[3 * HW];
    xq[(size_t)(b * 16 + q) * HW + pix] = v;
}

__device__ __forceinline__ unsigned pk_bf16(float lo, float hi) {
    unsigned a = __float_as_uint(lo), b = __float_as_uint(hi);
    return ((a + 0x8000u) >> 16) | ((b + 0x8000u) & 0xffff0000u);
}

// ---------------------------------------------------------------------------
// Fused deform (round-5 known-good). Block = 32 px, 256 thr.
// Phase 1: thread=(px,g): offsets/mask -> 9 taps bilinear -> bf16 into LDS.
// Phase 2: MFMA contraction vs Apack. One barrier.
// ---------------------------------------------------------------------------
__global__ __launch_bounds__(256, 4) void deform_fused_k(
    const float4* __restrict__ xq, const float* __restrict__ o4,
    const float* __restrict__ flow, const uint4* __restrict__ Apack,
    const float* __restrict__ bias, float* __restrict__ out)
{
    __shared__ u16 sv[32 * 584];   // 37,376 B

    const int bid = blockIdx.x;    // 2048
    const int b = bid >> 9;
    const int pix0 = (bid & 511) << 5;
    const int t = threadIdx.x;

    {
        const int gpx = t & 31, g = t >> 5;
        const int pix = pix0 + gpx;
        const int h = pix >> 7, w = pix & (WW - 1);
        const float fy = flow[((size_t)b * 2 + 1) * HW + pix];
        const float fx = flow[((size_t)b * 2 + 0) * HW + pix];
        const float* ob = o4 + (size_t)b * 216 * HW + pix;
        const float4* q0 = xq + (size_t)(b * 16 + g * 2) * HW;
        const float4* q1 = q0 + HW;

        int   code[9];
        float w00[9], w01[9], w10[9], w11[9];

#pragma unroll
        for (int k = 0; k < 9; ++k) {
            const float oy = ob[(size_t)(g * 18 + k * 2) * HW];
            const float ox = ob[(size_t)(g * 18 + k * 2 + 1) * HW];
            float mm = ob[(size_t)(144 + g * 9 + k) * HW];
            mm = __builtin_amdgcn_rcpf(1.f + __expf(-mm));

            const float ay = fabsf(oy), ax = fabsf(ox);
            const float ey = __expf(-2.f * ay), ex = __expf(-2.f * ax);
            float ty = (1.f - ey) * __builtin_amdgcn_rcpf(1.f + ey);
            float tx = (1.f - ex) * __builtin_amdgcn_rcpf(1.f + ex);
            ty = copysignf(ty, oy); tx = copysignf(tx, ox);

            const float ppy = 10.f * ty + fy + (float)(h + k / 3 - 1);
            const float ppx = 10.f * tx + fx + (float)(w + k % 3 - 1);

            const float y0f = floorf(ppy), x0f = floorf(ppx);
            const float ly = ppy - y0f, lx = ppx - x0f;
            const int iy0 = (int)y0f, ix0 = (int)x0f;
            const int iy1 = iy0 + 1,  ix1 = ix0 + 1;

            const float vy0 = (iy0 >= 0 && iy0 < HH) ? 1.f : 0.f;
            const float vy1 = (iy1 >= 0 && iy1 < HH) ? 1.f : 0.f;
            const float vx0 = (ix0 >= 0 && ix0 < WW) ? 1.f : 0.f;
            const float vx1 = (ix1 >= 0 && ix1 < WW) ? 1.f : 0.f;

            const int cy0 = min(max(iy0, 0), HH - 1);
            const int cy1 = min(max(iy1, 0), HH - 1);
            const int cx0 = min(max(ix0, 0), WW - 1);
            const int cx1 = min(max(ix1, 0), WW - 1);

            w00[k] = (1.f - ly) * (1.f - lx) * vy0 * vx0 * mm;
            w01[k] = (1.f - ly) * lx         * vy0 * vx1 * mm;
            w10[k] = ly         * (1.f - lx) * vy1 * vx0 * mm;
            w11[k] = ly         * lx         * vy1 * vx1 * mm;

            code[k] = (cy0 * WW + cx0) | ((cx1 - cx0) << 14) | ((cy1 - cy0) << 15);
        }

        u16* svp = sv + gpx * 584 + g * 72;
#pragma unroll
        for (int k = 0; k < 9; ++k) {
            const int i00 = code[k] & 16383;
            const int i01 = i00 + ((code[k] >> 14) & 1);
            const int i10 = i00 + (((code[k] >> 15) & 1) << 7);
            const int i11 = i10 + ((code[k] >> 14) & 1);

            const float4 a0 = q0[i00], a1 = q1[i00];
            const float4 b0 = q0[i01], b1 = q1[i01];
            const float4 c0 = q0[i10], c1 = q1[i10];
            const float4 d0 = q0[i11], d1 = q1[i11];
            const float W00 = w00[k], W01 = w01[k], W10 = w10[k], W11 = w11[k];

            float s0 = W00 * a0.x + W01 * b0.x + W10 * c0.x + W11 * d0.x;
            float s1 = W00 * a0.y + W01 * b0.y + W10 * c0.y + W11 * d0.y;
            float s2 = W00 * a0.z + W01 * b0.z + W10 * c0.z + W11 * d0.z;
            float s3 = W00 * a0.w + W01 * b0.w + W10 * c0.w + W11 * d0.w;
            float s4 = W00 * a1.x + W01 * b1.x + W10 * c1.x + W11 * d1.x;
            float s5 = W00 * a1.y + W01 * b1.y + W10 * c1.y + W11 * d1.y;
            float s6 = W00 * a1.z + W01 * b1.z + W10 * c1.z + W11 * d1.z;
            float s7 = W00 * a1.w + W01 * b1.w + W10 * c1.w + W11 * d1.w;

            uint4 P;
            P.x = pk_bf16(s0, s1);
            P.y = pk_bf16(s2, s3);
            P.z = pk_bf16(s4, s5);
            P.w = pk_bf16(s6, s7);
            *(uint4*)(svp + (size_t)k * 8) = P;
        }
    }
    __syncthreads();

    {
        const int lane = t & 63, wv = t >> 6;
        const int fr = lane & 15, fq = lane >> 4;

        f32x4 acc[2];
#pragma unroll
        for (int n = 0; n < 2; ++n) { acc[n][0] = 0.f; acc[n][1] = 0.f; acc[n][2] = 0.f; acc[n][3] = 0.f; }

#pragma unroll
        for (int kk = 0; kk < 18; ++kk) {
            const bf16x8 A = cvt8(Apack[((kk * 4 + fq) * 4 + wv) * 16 + fr]);
#pragma unroll
            for (int n = 0; n < 2; ++n) {
                const bf16x8 Bf = ld8(sv + (size_t)(n * 16 + fr) * 584 + kk * 32 + fq * 8);
                acc[n] = __builtin_amdgcn_mfma_f32_16x16x32_bf16(A, Bf, acc[n], 0, 0, 0);
            }
        }

        const float4 bv = *(const float4*)(bias + wv * 16 + 4 * fq);
        const float bb[4] = { bv.x, bv.y, bv.z, bv.w };
#pragma unroll
        for (int n = 0; n < 2; ++n) {
            const int pix = pix0 + n * 16 + fr;
#pragma unroll
            for (int i = 0; i < 4; ++i) {
                const int oc = wv * 16 + 4 * fq + i;
                out[((size_t)b * 64 + oc) * HW + pix] = acc[n][i] + bb[i];
            }
        }
    }
}

// ---------------------------------------------------------------------------
extern "C" void kernel_launch(void* const* d_in, const int* in_sizes, int n_in,
                              void* d_out, int out_size, void* d_ws, size_t ws_size,
                              hipStream_t stream)
{
    const float* x     = (const float*)d_in[0];
    const float* xw    = (const float*)d_in[1];
    const float* xc    = (const float*)d_in[2];
    const float* flow  = (const float*)d_in[3];
    const float* w1    = (const float*)d_in[4];
    const float* b1    = (const float*)d_in[5];
    const float* w2    = (const float*)d_in[6];
    const float* b2    = (const float*)d_in[7];
    const float* w3    = (const float*)d_in[8];
    const float* b3    = (const float*)d_in[9];
    const float* w4    = (const float*)d_in[10];
    const float* b4    = (const float*)d_in[11];
    const float* wt    = (const float*)d_in[12];
    const float* bias  = (const float*)d_in[13];
    float* out = (float*)d_out;

    char* ws = (char*)d_ws;
    // ws layout (total 91,579,392 B, identical to rounds 4/5):
    //   region0 [0, 56.6M)   : X1p (50.3M, conv1 packed input) -> o2 f32 -> o4
    //   buf1    @56,623,104  : o1 f32 -> o2p -> o3p           (16.8M)
    //   buf2    @73,400,320  : o1p -> o3 f32 -> xq            (16.8M)
    //   weights @90,177,536  : Apack, W1h/l, W2h/l, W3h/l, W4h/l, b4p
    u16*   X1p = (u16*)(ws);
    float* o4  = (float*)(ws);
    float* buf1 = (float*)(ws + 56623104);
    float* buf2 = (float*)(ws + 73400320);
    u16* Apack = (u16*)(ws + 90177536);
    u16* W1h = (u16*)(ws + 90251264);
    u16* W1l = (u16*)(ws + 90472448);
    u16* W2h = (u16*)(ws + 90693632);
    u16* W2l = (u16*)(ws + 90767360);
    u16* W3h = (u16*)(ws + 90841088);
    u16* W3l = (u16*)(ws + 90914816);
    u16* W4h = (u16*)(ws + 90988544);
    u16* W4l = (u16*)(ws + 91283456);
    float* b4p = (float*)(ws + 91578368);

    const dim3 blk(256);

    // ---- weight prep ----
    split_w_k<<<dim3((64 * 9 * 192 + 255) / 256), blk, 0, stream>>>(w1, W1h, W1l, 64, 64, 130, 192);
    split_w_k<<<dim3((64 * 9 * 64 + 255) / 256), blk, 0, stream>>>(w2, W2h, W2l, 64, 64, 64, 64);
    split_w_k<<<dim3((64 * 9 * 64 + 255) / 256), blk, 0, stream>>>(w3, W3h, W3l, 64, 64, 64, 64);
    split_w_k<<<dim3((256 * 9 * 64 + 255) / 256), blk, 0, stream>>>(w4, W4h, W4l, 216, 256, 64, 64);
    pad_bias_k<<<dim3(1), blk, 0, stream>>>(b4, b4p);
    pack_dw_k<<<dim3(144), blk, 0, stream>>>(wt, Apack);

    // ---- conv stack (packed split-bf16 inputs) ----
    // pack cat(xw,xc,flow) -> X1p (192-ch records) in region0
    pack_x_k<192, true><<<dim3(BB * HW / 256), blk, 0, stream>>>(xw, xc, flow, X1p);
    // conv1: 192(130) -> 64, lrelu; out f32 @ buf1
    conv_pk_k<3, true><<<dim3(128, 1, BB), blk, 0, stream>>>(X1p, W1h, W1l, b1, buf1, 64, 64);
    // pack o1 -> o1p @ buf2
    pack_x_k<64, false><<<dim3(BB * HW / 256), blk, 0, stream>>>(buf1, nullptr, nullptr, (u16*)buf2);
    // conv2: 64 -> 64, lrelu; out f32 @ region0 (X1p dead)
    conv_pk_k<1, true><<<dim3(128, 1, BB), blk, 0, stream>>>((u16*)buf2, W2h, W2l, b2, (float*)ws, 64, 64);
    // pack o2 -> o2p @ buf1 (o1 dead)
    pack_x_k<64, false><<<dim3(BB * HW / 256), blk, 0, stream>>>((float*)ws, nullptr, nullptr, (u16*)buf1);
    // conv3: 64 -> 64, lrelu; out f32 @ buf2 (o1p dead)
    conv_pk_k<1, true><<<dim3(128, 1, BB), blk, 0, stream>>>((u16*)buf1, W3h, W3l, b3, buf2, 64, 64);
    // pack o3 -> o3p @ buf1 (o2p dead)
    pack_x_k<64, false><<<dim3(BB * HW / 256), blk, 0, stream>>>(buf2, nullptr, nullptr, (u16*)buf1);
    // conv4: 64 -> 216 (pad 256), no act; out f32 o4 @ region0 (o2 dead)
    conv_pk_k<1, false><<<dim3(128, 4, BB), blk, 0, stream>>>((u16*)buf1, W4h, W4l, b4p, o4, 216, 216);

    // x -> channel-quad layout @ buf2 (o3 f32 dead after its pack)
    transpose_xq_k<<<dim3(BB * 16 * HW / 256), blk, 0, stream>>>(x, (float4*)buf2);

    deform_fused_k<<<dim3(BB * HW / 32), blk, 0, stream>>>(
        (const float4*)buf2, o4, flow, (const uint4*)Apack, bias, out);
}